// Round 1
// baseline (191.954 us; speedup 1.0000x reference)
//
#include <hip/hip_runtime.h>
#include <hip/hip_bf16.h>

#define N_PTS 8192
#define M_PTS 8192
#define DIM   512
#define NB    (N_PTS/128)   // 64 n-blocks

typedef __attribute__((ext_vector_type(8))) short bf8_t;   // 8 bf16 in 4 VGPRs
typedef __attribute__((ext_vector_type(4))) float f4_t;

// workspace layout (bytes)
constexpr size_t ZB_OFF   = 0;                                        // bf16 panels of z: 8 MiB
constexpr size_t EB_OFF   = (size_t)N_PTS * DIM * 2;                  // bf16 panels of e: 8 MiB
constexpr size_t Z2_OFF   = EB_OFF + (size_t)M_PTS * DIM * 2;         // f32 row norms z
constexpr size_t E2_OFF   = Z2_OFF + (size_t)N_PTS * 4;
constexpr size_t PMAX_OFF = E2_OFF + (size_t)M_PTS * 4;               // f32 [NB][M]
constexpr size_t PSUM_OFF = PMAX_OFF + (size_t)NB * M_PTS * 4;        // f32 [NB][M]
constexpr size_t LSE_OFF  = PSUM_OFF + (size_t)NB * M_PTS * 4;        // f32 [M]

__device__ __forceinline__ unsigned short f2bf(float x) {
  __hip_bfloat16 h = __float2bfloat16(x);
  return __builtin_bit_cast(unsigned short, h);
}

__device__ __forceinline__ void gload_lds16(const void* g, void* l) {
  __builtin_amdgcn_global_load_lds(
      (const __attribute__((address_space(1))) unsigned int*)g,
      (__attribute__((address_space(3))) unsigned int*)l, 16, 0, 0);
}

// ---------------------------------------------------------------------------
// Kernel 1: f32 -> bf16 panel-major swizzled layout + f32 row squared norms.
// Panel layout: panel pi = (row>>7)*8 + (k>>6), 128 rows x 64 k of bf16 =
// 16 KiB contiguous. Within panel: byte = (r*128 + c*2) ^ ((r&7)<<4).
// The XOR pre-swizzles the global image so global_load_lds can write LDS
// linearly and ds_read_b128 applies the same XOR (rule 21, G4 fix).
// ---------------------------------------------------------------------------
__global__ void conv_kernel(const float* __restrict__ z,
                            const float* __restrict__ e,
                            char* __restrict__ ws) {
  const int b = blockIdx.x;              // 0..16383
  const bool isE = b >= N_PTS;
  const int row = isE ? (b - N_PTS) : b;
  const float* src = (isE ? e : z) + (size_t)row * DIM;
  char* panels = ws + (isE ? EB_OFF : ZB_OFF);
  float* rowsq = (float*)(ws + (isE ? E2_OFF : Z2_OFF));

  const int t = threadIdx.x;             // 128 threads, 4 f32 each
  float4 v = ((const float4*)src)[t];
  float ss = v.x * v.x + v.y * v.y + v.z * v.z + v.w * v.w;

  ushort4 bv;
  bv.x = f2bf(v.x); bv.y = f2bf(v.y); bv.z = f2bf(v.z); bv.w = f2bf(v.w);

  const int k = t * 4;
  const int pi = (row >> 7) * (DIM / 64) + (k >> 6);
  const int r = row & 127;
  const int c = k & 63;
  const int byteoff = (r * 128 + c * 2) ^ ((r & 7) << 4);  // stays 8B-aligned
  *(ushort4*)(panels + (size_t)pi * 16384 + byteoff) = bv;

  #pragma unroll
  for (int mk = 32; mk >= 1; mk >>= 1) ss += __shfl_xor(ss, mk, 64);
  __shared__ float red[2];
  if ((t & 63) == 0) red[t >> 6] = ss;
  __syncthreads();
  if (t == 0) rowsq[row] = red[0] + red[1];
}

// ---------------------------------------------------------------------------
// Kernel 2: 128x128 tile GEMM (z . e^T) with fused per-column online
// (max, sum-exp) of  scale*(|z|^2 + |e|^2 - 2 dot). 4 waves 2x2, each wave a
// 64x64 subtile of 4x4 16x16x32 bf16 MFMA fragments, BK=64, K=512 (8 steps).
// ---------------------------------------------------------------------------
__global__ __launch_bounds__(256) void gemm_lse_kernel(char* __restrict__ ws,
                                                       const float* __restrict__ log_sigma) {
  __shared__ char lds[32768] __attribute__((aligned(16)));
  char* ldsA = lds;
  char* ldsB = lds + 16384;

  const int tid  = threadIdx.x;
  const int lane = tid & 63;
  const int wv   = tid >> 6;     // 0..3
  const int wr   = wv >> 1;      // row-wave 0..1  (n dim)
  const int wc   = wv & 1;       // col-wave 0..1  (m dim)
  const int mblk = blockIdx.x;   // 0..63  (e tiles)
  const int nblk = blockIdx.y;   // 0..63  (z tiles)

  const float lsv = log_sigma[0];
  const float sc  = -0.5f * __expf(-2.0f * lsv);   // alpha/T, T=1
  const float n2s = -2.0f * sc;

  f4_t acc[4][4] = {};

  const char* zb = ws + ZB_OFF;
  const char* eb = ws + EB_OFF;

  for (int kb = 0; kb < DIM / 64; ++kb) {
    const char* gA = zb + (size_t)(nblk * 8 + kb) * 16384;
    const char* gB = eb + (size_t)(mblk * 8 + kb) * 16384;
    #pragma unroll
    for (int j = 0; j < 4; ++j) {
      const int off  = j * 4096 + wv * 1024;          // wave-uniform chunk
      const int goff = off + (lane << 4);             // per-lane global
      gload_lds16(gA + goff, ldsA + off);
      gload_lds16(gB + goff, ldsB + off);
    }
    __syncthreads();   // vmcnt(0) drain + barrier (compiler-emitted)

    #pragma unroll
    for (int ks = 0; ks < 2; ++ks) {
      bf8_t a[4], b[4];
      const int kk2 = (ks * 32 + ((lane >> 4) << 3)) * 2;   // byte col
      #pragma unroll
      for (int f = 0; f < 4; ++f) {
        const int ra = wr * 64 + f * 16 + (lane & 15);
        a[f] = *(const bf8_t*)(ldsA + ((ra * 128 + kk2) ^ ((ra & 7) << 4)));
        const int rb = wc * 64 + f * 16 + (lane & 15);
        b[f] = *(const bf8_t*)(ldsB + ((rb * 128 + kk2) ^ ((rb & 7) << 4)));
      }
      #pragma unroll
      for (int i = 0; i < 4; ++i)
        #pragma unroll
        for (int j = 0; j < 4; ++j)
          acc[i][j] = __builtin_amdgcn_mfma_f32_16x16x32_bf16(a[i], b[j], acc[i][j], 0, 0, 0);
    }
    __syncthreads();   // protect single-buffered LDS before next stage
  }

  // ---- epilogue: per-column online (max, sumexp) over this block's 128 rows
  // C layout (m89): col = lane&15, row = (lane>>4)*4 + reg
  float z2v[4][4];
  {
    const float* z2p = (const float*)(ws + Z2_OFF) + nblk * 128 + wr * 64 + ((lane >> 4) << 2);
    #pragma unroll
    for (int i = 0; i < 4; ++i)
      #pragma unroll
      for (int r = 0; r < 4; ++r) z2v[i][r] = z2p[i * 16 + r];
  }
  float e2v[4];
  {
    const float* e2p = (const float*)(ws + E2_OFF) + mblk * 128 + wc * 64 + (lane & 15);
    #pragma unroll
    for (int j = 0; j < 4; ++j) e2v[j] = e2p[j * 16];
  }

  float* lmax = (float*)lds;            // [2][128] reuse tile LDS (post-barrier)
  float* lsum = (float*)(lds + 1024);

  #pragma unroll
  for (int j = 0; j < 4; ++j) {
    float vals[16];
    float mx = -1e30f;
    #pragma unroll
    for (int i = 0; i < 4; ++i)
      #pragma unroll
      for (int r = 0; r < 4; ++r) {
        float v = fmaf(n2s, acc[i][j][r], sc * (z2v[i][r] + e2v[j]));
        vals[i * 4 + r] = v;
        mx = fmaxf(mx, v);
      }
    float sm = 0.0f;
    #pragma unroll
    for (int q = 0; q < 16; ++q) sm += __expf(vals[q] - mx);

    // combine the 4 lanes sharing a column: lanes l, l^16, l^32, l^48
    #pragma unroll
    for (int mk = 16; mk <= 32; mk <<= 1) {
      float om = __shfl_xor(mx, mk, 64);
      float os = __shfl_xor(sm, mk, 64);
      float nm = fmaxf(mx, om);
      sm = sm * __expf(mx - nm) + os * __expf(om - nm);
      mx = nm;
    }
    if (lane < 16) {
      const int col = wc * 64 + j * 16 + lane;
      lmax[wr * 128 + col] = mx;
      lsum[wr * 128 + col] = sm;
    }
  }
  __syncthreads();

  if (tid < 128) {
    const float m0 = lmax[tid],       s0 = lsum[tid];
    const float m1 = lmax[128 + tid], s1 = lsum[128 + tid];
    const float Mx = fmaxf(m0, m1);
    const float S  = s0 * __expf(m0 - Mx) + s1 * __expf(m1 - Mx);
    float* pmax = (float*)(ws + PMAX_OFF);
    float* psum = (float*)(ws + PSUM_OFF);
    const size_t idx = (size_t)nblk * M_PTS + mblk * 128 + tid;
    pmax[idx] = Mx;
    psum[idx] = S;
  }
}

// ---------------------------------------------------------------------------
// Kernel 3: combine 64 n-block partials per column -> lse[m]
// ---------------------------------------------------------------------------
__global__ void combine_kernel(char* __restrict__ ws) {
  const int m = blockIdx.x * 256 + threadIdx.x;    // 8192 total
  const float* pmax = (const float*)(ws + PMAX_OFF);
  const float* psum = (const float*)(ws + PSUM_OFF);
  float Mx = pmax[m];
  float S  = psum[m];
  for (int nb = 1; nb < NB; ++nb) {
    const float pm = pmax[(size_t)nb * M_PTS + m];
    const float ps = psum[(size_t)nb * M_PTS + m];
    const float nm = fmaxf(Mx, pm);
    S = S * __expf(Mx - nm) + ps * __expf(pm - nm);
    Mx = nm;
  }
  ((float*)(ws + LSE_OFF))[m] = Mx + logf(S);
}

// ---------------------------------------------------------------------------
// Kernel 4: loss = -mean(lse) + 0.5*D*(2*ls - 1) + log(N)
// ---------------------------------------------------------------------------
__global__ void finalize_kernel(const char* __restrict__ ws,
                                const float* __restrict__ log_sigma,
                                float* __restrict__ out) {
  const float* lse = (const float*)(ws + LSE_OFF);
  double acc = 0.0;
  for (int i = threadIdx.x; i < M_PTS; i += 256) acc += (double)lse[i];
  #pragma unroll
  for (int mk = 32; mk >= 1; mk >>= 1) acc += __shfl_xor(acc, mk, 64);
  __shared__ double red[4];
  if ((threadIdx.x & 63) == 0) red[threadIdx.x >> 6] = acc;
  __syncthreads();
  if (threadIdx.x == 0) {
    const double total = red[0] + red[1] + red[2] + red[3];
    const double ls = (double)log_sigma[0];
    const double loss = -total / (double)M_PTS
                        + 0.5 * (double)DIM * (2.0 * ls - 1.0)
                        + log((double)N_PTS);
    out[0] = (float)loss;
  }
}

extern "C" void kernel_launch(void* const* d_in, const int* in_sizes, int n_in,
                              void* d_out, int out_size, void* d_ws, size_t ws_size,
                              hipStream_t stream) {
  const float* z  = (const float*)d_in[0];
  const float* e  = (const float*)d_in[1];
  const float* ls = (const float*)d_in[2];
  float* out = (float*)d_out;
  char* ws = (char*)d_ws;

  conv_kernel<<<N_PTS + M_PTS, 128, 0, stream>>>(z, e, ws);
  dim3 grid(M_PTS / 128, N_PTS / 128);
  gemm_lse_kernel<<<grid, 256, 0, stream>>>(ws, ls);
  combine_kernel<<<M_PTS / 256, 256, 0, stream>>>(ws);
  finalize_kernel<<<1, 256, 0, stream>>>(ws, ls, out);
}